// Round 1
// baseline (344.103 us; speedup 1.0000x reference)
//
#include <hip/hip_runtime.h>
#include <hip/hip_bf16.h>

typedef __bf16 bf16x8 __attribute__((ext_vector_type(8)));
typedef __bf16 bf16x4 __attribute__((ext_vector_type(4)));
typedef float  f32x4  __attribute__((ext_vector_type(4)));

#define NTOK 16384
#define DDIM 1024
#define HDIM 1024
#define NEXP 8

// workspace layout (bytes)
#define XB_OFF   0u          // bf16 x        [NTOK][DDIM]   33,554,432
#define WT_OFF   33554432u   // bf16 W^T      [E][H][D]      16,777,216
#define IDX_OFF  50331648u   // int  idx      [E][NTOK]         524,288
#define PRB_OFF  50855936u   // f32  prob     [E][NTOK]         524,288
#define TTE_OFF  51380224u   // int2 top2 idx [NTOK]            131,072
#define TTP_OFF  51511296u   // f32x2 top2 p  [NTOK]            131,072
#define CNT_OFF  51642368u   // int  counts   [8] + entropy acc (zeroed via memset)
#define ENT_OFF  51642400u

typedef __attribute__((address_space(1))) void gvoid_t;
typedef __attribute__((address_space(3))) void lvoid_t;

__device__ __forceinline__ void cp16(void* lds, const void* g) {
  // async global->LDS, 16B per lane; LDS dest = wave-uniform base + lane*16
  __builtin_amdgcn_global_load_lds((gvoid_t*)g, (lvoid_t*)lds, 16, 0, 0);
}

// ---------------- expert_w [E][D][H] f32  ->  W^T [E][H][D] bf16 ----------------
__global__ __launch_bounds__(256) void transpose_w(const float* __restrict__ w,
                                                   __bf16* __restrict__ wT) {
  const int e  = blockIdx.z;
  const int d0 = blockIdx.y * 64;
  const int h0 = blockIdx.x * 64;
  __shared__ float tile[64][68];  // +4 pad breaks bank aliasing on transpose read
  const int t = threadIdx.x;
  const float* base = w + ((size_t)e * DDIM + d0) * HDIM + h0;
#pragma unroll
  for (int it = 0; it < 4; ++it) {
    int dl = it * 16 + (t >> 4);
    int hl = (t & 15) * 4;
    float4 v = *(const float4*)(base + (size_t)dl * HDIM + hl);
    tile[dl][hl]     = v.x;
    tile[dl][hl + 1] = v.y;
    tile[dl][hl + 2] = v.z;
    tile[dl][hl + 3] = v.w;
  }
  __syncthreads();
  __bf16* obase = wT + ((size_t)e * HDIM + h0) * DDIM + d0;
#pragma unroll
  for (int it = 0; it < 4; ++it) {
    int hl = it * 16 + (t >> 4);
    int dl = (t & 15) * 4;
    bf16x4 bv;
    bv[0] = (__bf16)tile[dl][hl];
    bv[1] = (__bf16)tile[dl + 1][hl];
    bv[2] = (__bf16)tile[dl + 2][hl];
    bv[3] = (__bf16)tile[dl + 3][hl];
    *(bf16x4*)(obase + (size_t)hl * DDIM + dl) = bv;
  }
}

// ---------------- gating: logits, softmax, entropy, top-2, routing lists, x->bf16 --
__global__ __launch_bounds__(256) void gate_kernel(
    const float* __restrict__ x, const float* __restrict__ gw,
    const float* __restrict__ gb, __bf16* __restrict__ xb,
    int* __restrict__ idx_g, float* __restrict__ prob_g,
    int2* __restrict__ tt_e, float2* __restrict__ tt_p,
    int* __restrict__ cnt_g, float* __restrict__ ent_g) {
  __shared__ float gwT[8 * 1040];   // gate_w^T, row stride 1040 (pad)
  __shared__ int   lidx[8 * 64];
  __shared__ float lprob[8 * 64];
  __shared__ int   lcnt[8];
  __shared__ int   gbase[8];
  __shared__ float went[4];
  const int tid = threadIdx.x, w = tid >> 6, lane = tid & 63;
  if (tid < 8) lcnt[tid] = 0;
#pragma unroll
  for (int i = 0; i < 32; ++i) {  // load gate_w [D][8] transposed into LDS
    int lin = i * 256 + tid;
    gwT[(lin & 7) * 1040 + (lin >> 3)] = gw[lin];
  }
  __syncthreads();

  float entacc = 0.f;
  for (int t = 0; t < 8; ++t) {
    const int n = blockIdx.x * 32 + w * 8 + t;
    const float4* xr = (const float4*)(x + (size_t)n * DDIM);
    float acc[8] = {0.f, 0.f, 0.f, 0.f, 0.f, 0.f, 0.f, 0.f};
#pragma unroll
    for (int i = 0; i < 4; ++i) {
      float4 v = xr[i * 64 + lane];             // d = i*256 + lane*4 .. +3
      bf16x4 bv;
      bv[0] = (__bf16)v.x; bv[1] = (__bf16)v.y;
      bv[2] = (__bf16)v.z; bv[3] = (__bf16)v.w;
      *(bf16x4*)(xb + (size_t)n * DDIM + i * 256 + lane * 4) = bv;
#pragma unroll
      for (int e = 0; e < 8; ++e) {
        float4 g = *(const float4*)&gwT[e * 1040 + i * 256 + lane * 4];
        acc[e] += v.x * g.x + v.y * g.y + v.z * g.z + v.w * g.w;
      }
    }
#pragma unroll
    for (int e = 0; e < 8; ++e) {
      float s = acc[e];
      for (int off = 32; off; off >>= 1) s += __shfl_down(s, off);
      acc[e] = s;
    }
    if (lane == 0) {
      float p[8];
      float mx = -1e30f;
#pragma unroll
      for (int e = 0; e < 8; ++e) { p[e] = acc[e] + gb[e]; mx = fmaxf(mx, p[e]); }
      float s = 0.f;
#pragma unroll
      for (int e = 0; e < 8; ++e) { p[e] = expf(p[e] - mx); s += p[e]; }
      float inv = 1.0f / s;
      float ent = 0.f;
#pragma unroll
      for (int e = 0; e < 8; ++e) { p[e] *= inv; ent -= p[e] * logf(p[e] + 1e-10f); }
      entacc += ent;
      int e1 = 0; float p1 = p[0];
#pragma unroll
      for (int e = 1; e < 8; ++e) if (p[e] > p1) { p1 = p[e]; e1 = e; }
      int e2 = (e1 == 0) ? 1 : 0; float p2 = p[e2];
#pragma unroll
      for (int e = 0; e < 8; ++e) if (e != e1 && p[e] > p2) { p2 = p[e]; e2 = e; }
      tt_e[n] = make_int2(e1, e2);
      tt_p[n] = make_float2(p1, p2);
      int j = atomicAdd(&lcnt[e1], 1); lidx[e1 * 64 + j] = n; lprob[e1 * 64 + j] = p1;
      j = atomicAdd(&lcnt[e2], 1);     lidx[e2 * 64 + j] = n; lprob[e2 * 64 + j] = p2;
    }
  }
  if (lane == 0) went[w] = entacc;
  __syncthreads();
  if (tid < 8) gbase[tid] = atomicAdd(&cnt_g[tid], lcnt[tid]);
  if (tid == 0) atomicAdd(ent_g, went[0] + went[1] + went[2] + went[3]);
  __syncthreads();
#pragma unroll
  for (int e = 0; e < 8; ++e) {
    for (int j = tid; j < lcnt[e]; j += 256) {
      idx_g[e * NTOK + gbase[e] + j]  = lidx[e * 64 + j];
      prob_g[e * NTOK + gbase[e] + j] = lprob[e * 64 + j];
    }
  }
}

// ---------------- out[n] = p1*b[e1] + p2*b[e2] ----------------
__global__ __launch_bounds__(256) void init_out(const int2* __restrict__ tt_e,
                                                const float2* __restrict__ tt_p,
                                                const float* __restrict__ eb,
                                                float* __restrict__ out) {
  const int n = blockIdx.x, t = threadIdx.x;
  int2   ee = tt_e[n];
  float2 pp = tt_p[n];
  float4 v1 = ((const float4*)(eb + (size_t)ee.x * HDIM))[t];
  float4 v2 = ((const float4*)(eb + (size_t)ee.y * HDIM))[t];
  float4 r;
  r.x = pp.x * v1.x + pp.y * v2.x;
  r.y = pp.x * v1.y + pp.y * v2.y;
  r.z = pp.x * v1.z + pp.y * v2.z;
  r.w = pp.x * v1.w + pp.y * v2.w;
  ((float4*)(out + (size_t)n * HDIM))[t] = r;
}

// ---------------- grouped gathered GEMM, scatter-add epilogue ----------------
__global__ __launch_bounds__(256) void moe_gemm(
    const __bf16* __restrict__ xb, const __bf16* __restrict__ wT,
    const int* __restrict__ idx_g, const float* __restrict__ prob_g,
    const int* __restrict__ cnt_g, float* __restrict__ out) {
  const int e = blockIdx.z, gy = blockIdx.y, gx = blockIdx.x;
  const int cnt = cnt_g[e];
  if (gy * 128 >= cnt) return;

  __shared__ __bf16 Ash[128 * 64];
  __shared__ __bf16 Bsh[128 * 64];
  __shared__ int    tok_s[128];
  __shared__ float  p_s[128];

  const int tid = threadIdx.x, w = tid >> 6, lane = tid & 63;
  if (tid < 128) {
    int gm  = gy * 128 + tid;
    int src = (gm < cnt) ? gm : (cnt - 1);
    tok_s[tid] = idx_g[e * NTOK + src];
    p_s[tid]   = (gm < cnt) ? prob_g[e * NTOK + src] : 0.0f;
  }
  __syncthreads();

  f32x4 acc[4][4];
  const f32x4 zero = {0.f, 0.f, 0.f, 0.f};
#pragma unroll
  for (int mi = 0; mi < 4; ++mi)
#pragma unroll
    for (int ni = 0; ni < 4; ++ni) acc[mi][ni] = zero;

  const __bf16* wbase = wT + (size_t)e * HDIM * DDIM + (size_t)(gx * 128) * DDIM;
  const int wm = (w >> 1) * 64, wn = (w & 1) * 64;
  const int tq = lane >> 4, tr = lane & 15;
  const int rsub = lane >> 3, c = lane & 7;

  for (int kk = 0; kk < 16; ++kk) {
    const int k0 = kk * 64;
#pragma unroll
    for (int it = 0; it < 4; ++it) {  // stage A: 128 rows x 64 k (gathered)
      int rb = it * 32 + w * 8;
      int r  = rb + rsub;
      cp16((char*)Ash + rb * 128,
           xb + (size_t)tok_s[r] * DDIM + k0 + c * 8);
    }
#pragma unroll
    for (int it = 0; it < 4; ++it) {  // stage B: 128 n-rows x 64 k from W^T
      int rb = it * 32 + w * 8;
      int r  = rb + rsub;
      cp16((char*)Bsh + rb * 128,
           wbase + (size_t)r * DDIM + k0 + c * 8);
    }
    __syncthreads();
#pragma unroll
    for (int h = 0; h < 2; ++h) {
      bf16x8 a[4], b[4];
#pragma unroll
      for (int mi = 0; mi < 4; ++mi)
        a[mi] = *(const bf16x8*)((const char*)Ash + (wm + mi * 16 + tr) * 128 + h * 64 + tq * 16);
#pragma unroll
      for (int ni = 0; ni < 4; ++ni)
        b[ni] = *(const bf16x8*)((const char*)Bsh + (wn + ni * 16 + tr) * 128 + h * 64 + tq * 16);
#pragma unroll
      for (int mi = 0; mi < 4; ++mi)
#pragma unroll
        for (int ni = 0; ni < 4; ++ni)
          acc[mi][ni] = __builtin_amdgcn_mfma_f32_16x16x32_bf16(a[mi], b[ni], acc[mi][ni], 0, 0, 0);
    }
    __syncthreads();
  }

  // epilogue: C/D layout col=lane&15, row=quad*4+reg; scale by prob, scatter-add
#pragma unroll
  for (int mi = 0; mi < 4; ++mi) {
#pragma unroll
    for (int r = 0; r < 4; ++r) {
      int lr = wm + mi * 16 + tq * 4 + r;
      int gm = gy * 128 + lr;
      if (gm < cnt) {
        int   tok = tok_s[lr];
        float p   = p_s[lr];
        float* orow = out + (size_t)tok * HDIM + gx * 128 + wn + tr;
#pragma unroll
        for (int ni = 0; ni < 4; ++ni)
          atomicAdd(orow + ni * 16, p * acc[mi][ni][r]);
      }
    }
  }
}

// ---------------- scalar loss ----------------
__global__ void finalize(const float* __restrict__ ent_g, const int* __restrict__ cnt_g,
                         float* __restrict__ loss_out) {
  if (threadIdx.x == 0) {
    float ent = ent_g[0] / (float)NTOK;
    float pen = 0.f;
    for (int e = 0; e < 8; ++e) {
      float r = (float)cnt_g[e] / (float)NTOK - 0.3f;
      if (r > 0.f) pen += r;
    }
    loss_out[0] = 0.1f * ent + pen;
  }
}

extern "C" void kernel_launch(void* const* d_in, const int* in_sizes, int n_in,
                              void* d_out, int out_size, void* d_ws, size_t ws_size,
                              hipStream_t stream) {
  const float* x  = (const float*)d_in[0];
  const float* gw = (const float*)d_in[1];
  const float* gb = (const float*)d_in[2];
  const float* ew = (const float*)d_in[3];
  const float* eb = (const float*)d_in[4];
  float* out = (float*)d_out;
  char*  ws  = (char*)d_ws;

  __bf16* xb     = (__bf16*)(ws + XB_OFF);
  __bf16* wT     = (__bf16*)(ws + WT_OFF);
  int*    idx_g  = (int*)(ws + IDX_OFF);
  float*  prob_g = (float*)(ws + PRB_OFF);
  int2*   tt_e   = (int2*)(ws + TTE_OFF);
  float2* tt_p   = (float2*)(ws + TTP_OFF);
  int*    cnt_g  = (int*)(ws + CNT_OFF);
  float*  ent_g  = (float*)(ws + ENT_OFF);

  hipMemsetAsync(ws + CNT_OFF, 0, 64, stream);
  transpose_w<<<dim3(16, 16, 8), 256, 0, stream>>>(ew, wT);
  gate_kernel<<<dim3(NTOK / 32), 256, 0, stream>>>(x, gw, gb, xb, idx_g, prob_g,
                                                   tt_e, tt_p, cnt_g, ent_g);
  init_out<<<dim3(NTOK), 256, 0, stream>>>(tt_e, tt_p, eb, out);
  moe_gemm<<<dim3(8, 128, 8), 256, 0, stream>>>(xb, wT, idx_g, prob_g, cnt_g, out);
  finalize<<<1, 64, 0, stream>>>(ent_g, cnt_g, out + (size_t)NTOK * HDIM);
}